// Round 14
// baseline (329.549 us; speedup 1.0000x reference)
//
#include <hip/hip_runtime.h>

#define BB 256
#define SS 200
#define MM 32
#define KDIM 128
#define VDIM 256
#define QDIM 128
#define HH 64
#define NROWS 10001
#define NSAMP (BB*SS)
#define INDIM (VDIM+QDIM)
#define DHS 8192
#define DHMASK (DHS-1)
#define XR 16
#define CH2 20
#define NB_ATTN 2501

typedef unsigned long long u64;
typedef unsigned int u32;

__device__ __forceinline__ float fexp(float x){ return __builtin_amdgcn_exp2f(x * 1.44269504f); }
__device__ __forceinline__ float fsigm(float x){ return __builtin_amdgcn_rcpf(1.f + fexp(-x)); }
__device__ __forceinline__ float ftanh(float x){ return 1.f - 2.f*__builtin_amdgcn_rcpf(1.f + fexp(2.f*x)); }
__device__ __forceinline__ int clampq(int q){ return q < 0 ? 0 : (q > NROWS-1 ? NROWS-1 : q); }

__device__ __forceinline__ u32 hash64(u64 x){
  x ^= x >> 33; x *= 0xff51afd7ed558ccdULL;
  x ^= x >> 33; x *= 0xc4ceb9fe1a85ec53ULL;
  x ^= x >> 33;
  return (u32)x;
}

__device__ __forceinline__ u64 shflx64(u64 v, int m){
  int lo = __shfl_xor((int)(u32)v, m, 64);
  int hi = __shfl_xor((int)(u32)(v >> 32), m, 64);
  return ((u64)(u32)hi << 32) | (u32)lo;
}

// transposes + present init
__global__ void k_tr(const float* __restrict__ W_ih, const float* __restrict__ key_mem,
                     float* __restrict__ WQT4, float* __restrict__ KT,
                     float* __restrict__ WVT, u32* __restrict__ present){
  int idx = blockIdx.x*256 + threadIdx.x;
  if (idx < 131072) {
    int dd = idx & 3, j = (idx >> 2) & 255, d4 = idx >> 10;
    WQT4[idx] = W_ih[j*INDIM + VDIM + 4*d4 + dd];
  } else if (idx < 135168) {
    int t = idx - 131072;
    int m = t & 31, d = t >> 5; KT[t] = key_mem[m*KDIM + d];
  } else if (idx < 200704) {
    int t = idx - 135168;
    int j = t & 255, v = t >> 8; WVT[v*256 + j] = W_ih[j*INDIM + v];
  } else {
    int t = idx - 200704;
    if (t < NROWS) present[t] = 0u;
  }
}

// fused front: [0,2501) attn ; [2501,2533) vw ; [2533,2733) mark
__global__ __launch_bounds__(256) void k_front(
    const float* __restrict__ emb, const float* __restrict__ KT,
    const float* __restrict__ val, const float* __restrict__ WVT,
    const int* __restrict__ q_data,
    float* __restrict__ CW, u64* __restrict__ KEYT,
    float* __restrict__ VW, u32* __restrict__ present){
  int bid = blockIdx.x;
  if (bid < NB_ATTN) {
    int w = threadIdx.x >> 6, l = threadIdx.x & 63;
    int n = bid*4 + w;
    __shared__ float se[4][QDIM];
    bool valid = (n < NROWS);
    if (valid) {
      se[w][l]      = emb[n*QDIM + l];
      se[w][l + 64] = emb[n*QDIM + l + 64];
    }
    __syncthreads();
    int m = l & 31, half = l >> 5;
    float part = 0.f;
    if (valid)
      for (int d = 0; d < 64; ++d) part += se[w][half*64 + d] * KT[(half*64 + d)*32 + m];
    float logit = part + __shfl_xor(part, 32, 64);   // both halves now hold full logit(m)
    float mx = logit;
    #pragma unroll
    for (int msk = 16; msk >= 1; msk >>= 1) mx = fmaxf(mx, __shfl_xor(mx, msk, 64));
    float e = (l < 32) ? expf(logit - mx) : 0.f;     // precise expf: trit boundaries
    float sum = e;
    #pragma unroll
    for (int msk = 16; msk >= 1; msk >>= 1) sum += __shfl_xor(sum, msk, 64);
    float cw = e / sum;
    float wv = fminf((cw - 0.075f)/0.013f, (1.0f - cw)/0.912f);
    wv = fmaxf(wv, 0.f);
    int iv = (wv >= 0.6f) ? 2 : ((wv >= 0.1f) ? 1 : 0);
    int ee = (m < 16) ? m + 16 : m - 16;   // key = kh*3^16 + kl (reference packing)
    u64 p3 = 1;
    for (int i = 0; i < 31; ++i) if (i < ee) p3 *= 3ULL;
    u64 term = (valid && l < 32) ? (u64)iv * p3 : 0ULL;
    #pragma unroll
    for (int msk = 16; msk >= 1; msk >>= 1) term += shflx64(term, msk);
    if (valid && l < 32) CW[n*256 + m] = cw;
    if (valid && l == 0) KEYT[n] = term;
  } else if (bid < NB_ATTN + MM) {
    int m = bid - NB_ATTN, j = threadIdx.x;
    __shared__ float sval[VDIM];
    sval[j] = val[m*VDIM + j];
    __syncthreads();
    float a0=0.f, a1=0.f, a2=0.f, a3=0.f;
    for (int v = 0; v < VDIM; v += 4) {
      a0 += sval[v+0]*WVT[(v+0)*256 + j];
      a1 += sval[v+1]*WVT[(v+1)*256 + j];
      a2 += sval[v+2]*WVT[(v+2)*256 + j];
      a3 += sval[v+3]*WVT[(v+3)*256 + j];
    }
    VW[m*256 + j] = (a0+a1)+(a2+a3);
  } else {
    int i = (bid - NB_ATTN - MM)*256 + threadIdx.x;
    if (i < NSAMP) present[clampq(q_data[i])] = 1u;
  }
}

// fused dedup + rank + per-row rank: single workgroup, LDS hash stays resident
__global__ __launch_bounds__(1024) void k_dedup2(
    const u32* __restrict__ present, const u64* __restrict__ KEYT,
    u64* __restrict__ uniq, u32* __restrict__ RANK, u32* __restrict__ RANKQ){
  __shared__ u32 sh_tab[DHS];
  __shared__ u32 sh_pay[DHS];
  __shared__ u32 sh_cnt;
  int tid = threadIdx.x;
  for (int i = tid; i < DHS; i += 1024) sh_tab[i] = 0u;
  if (tid == 0) sh_cnt = 0u;
  __syncthreads();
  for (int n = tid; n < NROWS; n += 1024) {
    if (present[n] != 1u) continue;
    u64 key = KEYT[n];
    u32 h = hash64(key) & DHMASK;
    while (true) {
      u32 cur = sh_tab[h];
      if (cur != 0u) {
        if (KEYT[cur-1u] == key) break;
        h = (h + 1) & DHMASK; continue;
      }
      u32 prev = atomicCAS(&sh_tab[h], 0u, (u32)(n + 1));
      if (prev == 0u) {
        u32 idx = atomicAdd(&sh_cnt, 1u);
        uniq[idx] = key;
        sh_pay[h] = idx;
        break;
      }
      if (KEYT[prev-1u] == key) break;
      h = (h + 1) & DHMASK;
    }
  }
  __threadfence();
  __syncthreads();
  u32 U = sh_cnt;
  // rank: U ~ hundreds; uniq is L1/L2-resident broadcast
  for (int u = tid; u < (int)U; u += 1024) {
    u64 k = uniq[u];
    u32 cnt = 0;
    for (u32 j = 0; j < U; ++j) cnt += (uniq[j] < k) ? 1u : 0u;
    RANK[u] = cnt;
  }
  __threadfence();
  __syncthreads();
  // per present row: read-only probes on resident LDS table
  for (int n = tid; n < NROWS; n += 1024) {
    if (present[n] != 1u) continue;
    u64 key = KEYT[n];
    u32 h = hash64(key) & DHMASK;
    while (true) {
      u32 cur = sh_tab[h];
      if (cur != 0u && KEYT[cur-1u] == key) { RANKQ[n] = RANK[sh_pay[h]]; break; }
      h = (h + 1) & DHMASK;
    }
  }
}

// XW4 row = bias + cw.VW + emb.WqT: 16 rows/block tiled GEMM
__global__ __launch_bounds__(256) void k_xw(
    const float* __restrict__ CW, const float* __restrict__ emb,
    const float* __restrict__ VW, const float* __restrict__ WQT4,
    const float* __restrict__ b_ih, const float* __restrict__ b_hh,
    float* __restrict__ XW4){
  int base = blockIdx.x * XR;
  int j = threadIdx.x;
  __shared__ float scw[XR][32];
  __shared__ __align__(16) float ses[XR][QDIM];
  for (int idx = j; idx < XR*32; idx += 256) {
    int r = idx >> 5, m = idx & 31, n = base + r;
    scw[r][m] = (n < NROWS) ? CW[n*256 + m] : 0.f;
  }
  for (int idx = j; idx < XR*QDIM; idx += 256) {
    int r = idx >> 7, d = idx & 127, n = base + r;
    ses[r][d] = (n < NROWS) ? emb[n*QDIM + d] : 0.f;
  }
  __syncthreads();
  float bias = b_ih[j] + b_hh[j];
  float acc[XR];
  #pragma unroll
  for (int r = 0; r < XR; ++r) acc[r] = bias;
  for (int m = 0; m < MM; ++m) {
    float wv = VW[m*256 + j];
    #pragma unroll
    for (int r = 0; r < XR; ++r) acc[r] += scw[r][m] * wv;
  }
  for (int d4 = 0; d4 < QDIM/4; ++d4) {
    float4 wq = *(const float4*)(WQT4 + d4*1024 + j*4);
    #pragma unroll
    for (int r = 0; r < XR; ++r) {
      float4 ev = *(const float4*)(&ses[r][4*d4]);
      acc[r] += ev.x*wq.x + ev.y*wq.y + ev.z*wq.z + ev.w*wq.w;
    }
  }
  int gate = j >> 6, unit = j & 63;
  #pragma unroll
  for (int r = 0; r < XR; ++r)
    if (base + r < NROWS) XW4[(size_t)(base + r)*256 + 4*unit + gate] = acc[r];
}

__global__ void k_ids(const int* __restrict__ q_data, const u32* __restrict__ RANKQ,
                      float* __restrict__ out_ids){
  int i = blockIdx.x*blockDim.x + threadIdx.x;
  if (i >= NSAMP) return;
  out_ids[i] = (float)RANKQ[clampq(q_data[i])];
}

// LSTM v4: TWO batch elements per block (8 waves) -> 2 waves/SIMD, so one chain's
// barrier/LDS/transcendental latency hides behind the other's compute.
// Per element: v3 layout (wave w owns units 16w..16w+15; lane=(g,u); hfull
// replicated; gate exchange via 3 shfl_xor; one barrier/step; LDS-only drains).
__global__ __launch_bounds__(512, 1) void k_lstm(
    const int* __restrict__ q_data, const float* __restrict__ XW4,
    const float* __restrict__ W_hh,
    const float* __restrict__ W_pred, const float* __restrict__ b_pred,
    const float* __restrict__ init_h, const float* __restrict__ init_c,
    float* __restrict__ out_pred){
  const int t = threadIdx.x;
  const int e = t >> 8, tl = t & 255;
  const int w = tl >> 6, l = t & 63;
  const int g = l >> 4, u = l & 15;
  const int unit = w*16 + u;
  const int b = blockIdx.x*2 + e;
  __shared__ float XWc[2][CH2][256];              // 40,960 B
  __shared__ __align__(16) float Hbuf[2][SS][68]; // 108,800 B (h history, 2-way banks)
  __shared__ float swp[HH];
  __shared__ int   sq[2][SS];
  for (int s = tl; s < SS; s += 256) sq[e][s] = clampq(q_data[b*SS + s]);
  if (t < HH) swp[t] = W_pred[t];

  float wgt[HH];                        // W_hh row (g*64 + unit)
  {
    const float4* wr = (const float4*)(W_hh + (size_t)(g*HH + unit)*HH);
    #pragma unroll
    for (int j4 = 0; j4 < HH/4; ++j4) {
      float4 v = wr[j4];
      wgt[4*j4+0]=v.x; wgt[4*j4+1]=v.y; wgt[4*j4+2]=v.z; wgt[4*j4+3]=v.w;
    }
  }
  float hfull[HH];                      // replicated h
  {
    const float4* ih = (const float4*)(init_h + b*HH);
    #pragma unroll
    for (int j4 = 0; j4 < HH/4; ++j4) {
      float4 v = ih[j4];
      hfull[4*j4+0]=v.x; hfull[4*j4+1]=v.y; hfull[4*j4+2]=v.z; hfull[4*j4+3]=v.w;
    }
  }
  float c  = init_c[b*HH + unit];
  float bp = b_pred[0];
  __syncthreads();

  for (int cs = 0; cs < SS; cs += CH2) {
    for (int rr = w; rr < CH2; rr += 4) {          // 5 rows per wave
      float4 xv = *(const float4*)(XW4 + (size_t)sq[e][cs + rr]*256 + 4*l);
      int wp = l >> 4, up = l & 15;
      XWc[e][rr][wp*64 +  0 + up] = xv.x;
      XWc[e][rr][wp*64 + 16 + up] = xv.y;
      XWc[e][rr][wp*64 + 32 + up] = xv.z;
      XWc[e][rr][wp*64 + 48 + up] = xv.w;
    }
    __syncthreads();
    for (int sl = 0; sl < CH2; ++sl) {
      const int s = cs + sl;
      float a0=0.f, a1=0.f, a2=0.f, a3=0.f;
      #pragma unroll
      for (int j = 0; j < 16; ++j) {
        a0 += wgt[j   ]*hfull[j   ];
        a1 += wgt[j+16]*hfull[j+16];
        a2 += wgt[j+32]*hfull[j+32];
        a3 += wgt[j+48]*hfull[j+48];
      }
      float a = XWc[e][sl][w*64 + l] + ((a0+a1)+(a2+a3));
      float v1 = __shfl_xor(a, 16, 64);
      float v2 = __shfl_xor(a, 32, 64);
      float v3 = __shfl_xor(v1, 32, 64);
      float vv[4] = {a, v1, v2, v3};
      float ii = vv[g], ff = vv[g^1], gg = vv[g^2], oo = vv[g^3];
      c = fsigm(ff)*c + fsigm(ii)*ftanh(gg);
      float hh = fsigm(oo)*ftanh(c);
      if (g == 0) Hbuf[e][s][unit] = hh;
      __syncthreads();                             // LDS-only drain
      const float4* hb = (const float4*)(&Hbuf[e][s][0]);  // uniform broadcast
      #pragma unroll
      for (int j4 = 0; j4 < HH/4; ++j4) {
        float4 v = hb[j4];
        hfull[4*j4+0]=v.x; hfull[4*j4+1]=v.y; hfull[4*j4+2]=v.z; hfull[4*j4+3]=v.w;
      }
    }
  }
  __syncthreads();
  if (tl < SS) {
    float acc = 0.f;
    #pragma unroll 16
    for (int kk = 0; kk < HH; ++kk) {
      int k2 = (kk + tl) & 63;          // swizzle: conflict-free banks
      acc += Hbuf[e][tl][k2] * swp[k2];
    }
    out_pred[b*SS + tl] = fsigm(acc + bp);
  }
}

extern "C" void kernel_launch(void* const* d_in, const int* in_sizes, int n_in,
                              void* d_out, int out_size, void* d_ws, size_t ws_size,
                              hipStream_t stream) {
  const int*   q_data  = (const int*)d_in[0];
  const float* emb     = (const float*)d_in[1];
  const float* keym    = (const float*)d_in[2];
  const float* val     = (const float*)d_in[3];
  const float* W_ih    = (const float*)d_in[4];
  const float* W_hh    = (const float*)d_in[5];
  const float* b_ih    = (const float*)d_in[6];
  const float* b_hh    = (const float*)d_in[7];
  const float* W_pred  = (const float*)d_in[8];
  const float* b_pred  = (const float*)d_in[9];
  const float* init_h  = (const float*)d_in[10];
  const float* init_c  = (const float*)d_in[11];

  char* ws = (char*)d_ws;
  float* XW4     = (float*)(ws + 0);          // 10,241,024 (CW overlaid low 32 floats/row)
  float* VW      = (float*)(ws + 10241024);   // 32,768
  u64*  KEYT     = (u64*) (ws + 10273792);    // 80,128
  u64*  uniq     = (u64*) (ws + 10353920);    // 80,128
  u32*  RANK     = (u32*) (ws + 10434048);    // 40,192
  u32*  present  = (u32*) (ws + 10539840);    // 40,064
  u32*  RANKQ    = (u32*) (ws + 10579904);    // 40,064
  float* WQT4    = (float*)(ws + 10619968);   // 524,288
  float* KT      = (float*)(ws + 11144256);   // 16,384
  float* WVT     = (float*)(ws + 11160640);   // 262,144
  float* CW      = XW4;                       // overlay: CW[n*256+m]

  float* out_pred = (float*)d_out;
  float* out_ids  = out_pred + NSAMP;

  hipLaunchKernelGGL(k_tr,     dim3(824), dim3(256), 0, stream,
                     W_ih, keym, WQT4, KT, WVT, present);
  hipLaunchKernelGGL(k_front,  dim3(NB_ATTN + MM + 200), dim3(256), 0, stream,
                     emb, KT, val, WVT, q_data, CW, KEYT, VW, present);
  hipLaunchKernelGGL(k_dedup2, dim3(1), dim3(1024), 0, stream,
                     present, KEYT, uniq, RANK, RANKQ);
  hipLaunchKernelGGL(k_xw,     dim3((NROWS+XR-1)/XR), dim3(256), 0, stream,
                     CW, emb, VW, WQT4, b_ih, b_hh, XW4);
  hipLaunchKernelGGL(k_ids,    dim3((NSAMP+255)/256), dim3(256), 0, stream,
                     q_data, RANKQ, out_ids);
  hipLaunchKernelGGL(k_lstm,   dim3(BB/2), dim3(512), 0, stream,
                     q_data, XW4, W_hh, W_pred, b_pred, init_h, init_c, out_pred);
}